// Round 11
// baseline (2291.956 us; speedup 1.0000x reference)
//
#include <hip/hip_runtime.h>
#include <cstdint>
#include <cstddef>

typedef unsigned short u16;
typedef short bf16x8 __attribute__((ext_vector_type(8)));
typedef float f32x4 __attribute__((ext_vector_type(4)));

union F16B { float4 f; f32x4 fv; bf16x8 v; u16 u[8]; };
union U4 { f32x4 f; uint32_t u[4]; };

#define SENT 0x7FC07FC0u   // two bf16 NaNs; GRU h is tanh-bounded -> never NaN

__device__ __forceinline__ u16 f2b(float f) {
  uint32_t x = __float_as_uint(f);
  return (u16)((x + 0x7FFFu + ((x >> 16) & 1u)) >> 16);
}
__device__ __forceinline__ float b2f(u16 h) { return __uint_as_float(((uint32_t)h) << 16); }
__device__ __forceinline__ float sigm(float x) { return 1.0f / (1.0f + __expf(-x)); }
__device__ __forceinline__ float tanh_(float x) { return 1.0f - 2.0f / (__expf(2.0f * x) + 1.0f); }
__device__ __forceinline__ float splus(float x) { return logf(1.0f + __expf(x)); }
__device__ __forceinline__ bf16x8 asbf(f32x4 x) { F16B u; u.fv = x; return u.v; }
__device__ __forceinline__ uint32_t umin_(uint32_t a, uint32_t b) { return a < b ? a : b; }

__device__ __forceinline__ void llc_st128(u16* p, f32x4 v) {
  asm volatile("global_store_dwordx4 %0, %1, off sc0 sc1" :: "v"(p), "v"(v) : "memory");
}

// ---------------- sizes ----------------
// B=128 N=512 H=512 L=256 P=3 T=511
constexpr size_t OFF_AIH   = 32768;      // 1536*4 f32
constexpr size_t OFF_CIH   = 57344;      // 1536 f32
constexpr size_t OFF_AK    = 63488;      // 512*4 f32
constexpr size_t OFF_CK    = 71680;      // 512 f32
constexpr size_t OFF_AMU2  = 73728;
constexpr size_t OFF_CMU2  = 73792;
constexpr size_t OFF_ALV2  = 73856;
constexpr size_t OFF_CLV2  = 73920;
constexpr size_t OFF_WHH   = 336128;     // 1572864 B
constexpr size_t OFF_WQ    = 1908992;    // 524288 B
constexpr size_t OFF_KF    = 2433280;    // 67108864 B
constexpr size_t OFF_QF    = 69542144;   // (Qf eliminated by fusion; ring lives here)
constexpr size_t OFF_RING  = OFF_QF;     // 3 slots x 8rt x 16kt x 64 x 8 bf16 = 393216 B
constexpr size_t OFF_HS    = 136651008;  // 66977792 B

// ---------------- init: zero out, sentinel-fill ring slots 1,2 ----------------
__global__ void k_zero(float* out, uint32_t* ring32) {
  int tid = blockIdx.x * 1024 + threadIdx.x;   // grid 64 x 1024 = 65536
  if (tid < 384) out[tid] = 0.f;
  ring32[32768 + tid] = SENT;                  // dwords [32768,98304) = slots 1,2
}

// fold rank-4 matrices: A = W @ W_ne (rows x 4), c = b + W @ b_ne
__global__ void k_fold(const float* __restrict__ Wih, const float* __restrict__ bih,
                       const float* __restrict__ Wk,  const float* __restrict__ bk,
                       const float* __restrict__ Wmu, const float* __restrict__ bmu,
                       const float* __restrict__ Wlv, const float* __restrict__ blv,
                       const float* __restrict__ Wne, const float* __restrict__ bne,
                       float* Aih, float* cih, float* Ak, float* ck,
                       float* Amu2, float* cmu2, float* Alv2, float* clv2) {
  int tid = blockIdx.x * 256 + threadIdx.x;
  if (tid >= 2054 * 5) return;
  int row = tid / 5, c = tid % 5;
  const float* wrow; float bias; float* Adst; float* cdst;
  if (row < 1536)      { wrow = Wih + (size_t)row * 512;              bias = bih[row];      Adst = Aih  + row * 4;        cdst = cih  + row; }
  else if (row < 2048) { int j = row - 1536; wrow = Wk + (size_t)j * 512;       bias = bk[j];  Adst = Ak   + j * 4; cdst = ck   + j; }
  else if (row < 2051) { int j = row - 2048; wrow = Wmu + (size_t)j * 1024 + 512; bias = bmu[j]; Adst = Amu2 + j * 4; cdst = cmu2 + j; }
  else                 { int j = row - 2051; wrow = Wlv + (size_t)j * 1024 + 512; bias = blv[j]; Adst = Alv2 + j * 4; cdst = clv2 + j; }
  float acc = 0.f;
  if (c < 4) { for (int h = 0; h < 512; ++h) acc += wrow[h] * Wne[h * 4 + c]; Adst[c] = acc; }
  else       { for (int h = 0; h < 512; ++h) acc += wrow[h] * bne[h];         cdst[0] = bias + acc; }
}

// h0 = tanh(z @ Wzh^T + bzh) -> ring slot 0 in FRAGMENT layout
// ring[slot][rt][kt][lane][e] = h(row = rt*16 + (lane&15), unit = kt*32 + (lane>>4)*8 + e)
__global__ void k_h0(const float* __restrict__ z, const float* __restrict__ Wzh,
                     const float* __restrict__ bzh, u16* __restrict__ ring) {
  int tid = blockIdx.x * 256 + threadIdx.x;   // 8192 = 128 rows * 64 unit-groups
  int row = tid >> 6, ug = tid & 63;
  const float* zr = z + row * 256;
  F16B o;
  #pragma unroll
  for (int e = 0; e < 8; ++e) {
    int u = ug * 8 + e;
    float acc = bzh[u];
    const float* wr = Wzh + (size_t)u * 256;
    for (int k = 0; k < 256; ++k) acc += zr[k] * wr[k];
    o.u[e] = f2b(tanh_(acc));
  }
  int rt = row >> 4, kt = ug >> 2, sub = ug & 3;
  int lane = sub * 16 + (row & 15);
  *(float4*)(ring + (size_t)(((rt * 16 + kt) * 64 + lane) * 8)) = o.f;
}

// convert (rows x 512) f32 weight into MFMA B-fragment tile layout, bf16
__global__ void k_wcvt(const float* __restrict__ W, u16* __restrict__ dst, int ntiles) {
  int tid = blockIdx.x * 256 + threadIdx.x;
  if (tid >= ntiles * 1024) return;
  int rem = tid & 1023, l = rem & 63;
  int nt = tid >> 10, kt = rem >> 6;
  int row = nt * 16 + (l & 15);
  int kb = kt * 32 + (l >> 4) * 8;
  const float* src = W + (size_t)row * 512 + kb;
  F16B o;
  #pragma unroll
  for (int e = 0; e < 8; ++e) o.u[e] = f2b(src[e]);
  *(float4*)(dst + (size_t)tid * 8) = o.f;
}

// K fragments: Kf[b][nt][kt][lane][8] = K[b][n][k] with K = feat @ Ak^T + ck
__global__ void k_kfrag(const float* __restrict__ tpos, const float* __restrict__ Ak,
                        const float* __restrict__ ck, u16* __restrict__ Kf) {
  int tid = blockIdx.x * 256 + threadIdx.x;   // 128*32768
  int b = tid >> 15, rem = tid & 32767;
  int r2 = rem & 1023, l = r2 & 63;
  int nt = rem >> 10, kt = r2 >> 6;
  int n = nt * 16 + (l & 15);
  int kb = kt * 32 + (l >> 4) * 8;
  float f0 = 0.f, f1 = 0.f, f2 = 0.f;
  if (n > 0) { const float* fp = tpos + ((size_t)b * 512 + n) * 3; f0 = fp[0]; f1 = fp[1]; f2 = fp[2]; }
  F16B o;
  #pragma unroll
  for (int e = 0; e < 8; ++e) {
    int hh = kb + e;
    o.u[e] = f2b(ck[hh] + f0 * Ak[hh * 4] + f1 * Ak[hh * 4 + 1] + f2 * Ak[hh * 4 + 2]);
  }
  *(float4*)(Kf + (size_t)tid * 8) = o.f;
}

// ---------------- GRU: weight-stationary, sentinel-polled 3-slot ring, flag-free ----------------
// Round-6 proven LLC protocol. This round's deltas (pure reordering + scheduler hint):
//  - Hs store delayed one step, issued POST-poll (HBM ack overlaps compute, off the poll chain)
//  - tpos prefetched one step ahead, issued POST-poll (off the poll chain)
//  - s_setprio(1) around MFMA+gates: computing waves out-arbitrate spinning waves on the CU
__global__ __launch_bounds__(256, 1) void k_gru(
    const float* __restrict__ tpos, const float* __restrict__ Aih, const float* __restrict__ cih,
    const float* __restrict__ bhh, const u16* __restrict__ whh,
    u16* __restrict__ ring, u16* __restrict__ Hs) {
  const int bid = blockIdx.x;
  const int half = bid & 1;
  const int g = bid >> 1;
  const int tid = threadIdx.x;
  const int w = tid >> 6;
  const int l = tid & 63;
  const int fl = l & 15, fh = l >> 4;
  __shared__ F16B wsm[3072];                    // 48 KB: 3 n-tiles x 16 k-tiles x 64 lanes
  __shared__ __align__(16) u16 trn[4][384];     // per-wave 16x16 transpose tile, stride 24 u16

  {
    const float4* src = (const float4*)whh;
    #pragma unroll
    for (int it = 0; it < 12; ++it) {
      int i = it * 256 + tid;               // 0..3071
      int ntl = i >> 10;
      int rem = i & 1023;
      int gnt = (ntl == 0) ? g : (ntl == 1 ? 32 + g : 64 + g);
      wsm[i].f = src[(size_t)gnt * 1024 + rem];
    }
  }
  const int jj = (g << 4) + fl;
  const float Ar0 = Aih[jj*4], Ar1 = Aih[jj*4+1], Ar2 = Aih[jj*4+2];
  const float Au0 = Aih[(512+jj)*4], Au1 = Aih[(512+jj)*4+1], Au2 = Aih[(512+jj)*4+2];
  const float An0 = Aih[(1024+jj)*4], An1 = Aih[(1024+jj)*4+1], An2 = Aih[(1024+jj)*4+2];
  const float cr = cih[jj] + bhh[jj];
  const float cu = cih[512+jj] + bhh[512+jj];
  const float cn = cih[1024+jj];
  const float bhn = bhh[1024+jj];
  const int rowbase = half * 64 + (w << 4);
  const int rt = (half << 2) + w;               // this wave's row-tile

  // hprev (this lane's 4 (row,unit) slots) from ring slot 0 fragment layout
  float hprev[4];
  {
    int kt_h = g >> 1;
    int sub_h = ((g & 1) << 1) | (fl >> 3);
    int e_h = fl & 7;
    #pragma unroll
    for (int i = 0; i < 4; ++i) {
      int lr = (fh << 2) + i;
      hprev[i] = b2f(ring[(size_t)(((rt * 16 + kt_h) * 64 + sub_h * 16 + lr) * 8 + e_h)]);
    }
  }
  // producer store mapping: chunk (cl=row-local, cs=8-unit-group)
  const int cl = fl;
  const int cs = fh & 1;
  u16* Tw = &trn[w][0];
  u16* rdst_base = ring + ((size_t)(rt * 16 + (g >> 1)) * 64 + ((((g & 1) << 1) | cs) * 16 + cl)) * 8;
  const u16* abase0 = ring + ((size_t)(rt * 16) * 64 + l) * 8;
  f32x4 sentv;
  sentv[0] = sentv[1] = sentv[2] = sentv[3] = __uint_as_float(SENT);
  __syncthreads();

  int cur = 0;                                  // slot holding h(t)
  float pf0[4] = {0.f,0.f,0.f,0.f}, pf1[4] = {0.f,0.f,0.f,0.f}, pf2[4] = {0.f,0.f,0.f,0.f};
  f32x4 prevChunk = {0.f,0.f,0.f,0.f};          // Hs chunk of step t-1 (delayed store)

  for (int t = 0; t < 511; ++t) {
    int wr = cur + 1;  if (wr == 3) wr = 0;     // slot for h(t+1)
    int clr = wr + 1;  if (clr == 3) clr = 0;   // slot to re-sentinel (== (t+2)%3)

    // poll slot 'cur': 16 coherent 16B loads; ready when no dword is sentinel.
    // On success the fragments are ALREADY in registers (no separate load RT).
    const u16* b0 = abase0 + ((size_t)cur << 16);
    const u16* b1 = b0 + 2048;
    const u16* b2 = b0 + 4096;
    const u16* b3 = b0 + 6144;
    f32x4 a0,a1,a2,a3,a4,a5,a6,a7,a8,a9,a10,a11,a12,a13,a14,a15;
    while (true) {
      asm volatile(
        "global_load_dwordx4 %0, %16, off sc0 sc1\n\t"
        "global_load_dwordx4 %1, %16, off offset:1024 sc0 sc1\n\t"
        "global_load_dwordx4 %2, %16, off offset:2048 sc0 sc1\n\t"
        "global_load_dwordx4 %3, %16, off offset:3072 sc0 sc1\n\t"
        "global_load_dwordx4 %4, %17, off sc0 sc1\n\t"
        "global_load_dwordx4 %5, %17, off offset:1024 sc0 sc1\n\t"
        "global_load_dwordx4 %6, %17, off offset:2048 sc0 sc1\n\t"
        "global_load_dwordx4 %7, %17, off offset:3072 sc0 sc1\n\t"
        "global_load_dwordx4 %8, %18, off sc0 sc1\n\t"
        "global_load_dwordx4 %9, %18, off offset:1024 sc0 sc1\n\t"
        "global_load_dwordx4 %10, %18, off offset:2048 sc0 sc1\n\t"
        "global_load_dwordx4 %11, %18, off offset:3072 sc0 sc1\n\t"
        "global_load_dwordx4 %12, %19, off sc0 sc1\n\t"
        "global_load_dwordx4 %13, %19, off offset:1024 sc0 sc1\n\t"
        "global_load_dwordx4 %14, %19, off offset:2048 sc0 sc1\n\t"
        "global_load_dwordx4 %15, %19, off offset:3072 sc0 sc1\n\t"
        "s_waitcnt vmcnt(0)"
        : "=&v"(a0),"=&v"(a1),"=&v"(a2),"=&v"(a3),"=&v"(a4),"=&v"(a5),"=&v"(a6),"=&v"(a7),
          "=&v"(a8),"=&v"(a9),"=&v"(a10),"=&v"(a11),"=&v"(a12),"=&v"(a13),"=&v"(a14),"=&v"(a15)
        : "v"(b0),"v"(b1),"v"(b2),"v"(b3)
        : "memory");
      __builtin_amdgcn_sched_barrier(0);
      uint32_t mn = 0xFFFFFFFFu;
#define CHK(R) { U4 x; x.f = (R); \
      mn = umin_(mn, x.u[0]^SENT); mn = umin_(mn, x.u[1]^SENT); \
      mn = umin_(mn, x.u[2]^SENT); mn = umin_(mn, x.u[3]^SENT); }
      CHK(a0) CHK(a1) CHK(a2) CHK(a3) CHK(a4) CHK(a5) CHK(a6) CHK(a7)
      CHK(a8) CHK(a9) CHK(a10) CHK(a11) CHK(a12) CHK(a13) CHK(a14) CHK(a15)
#undef CHK
      if (__ballot(mn == 0u) == 0ull) break;
    }
    __builtin_amdgcn_sched_barrier(0);

    // ---- post-poll issue window (all acks overlap the MFMA/gates below) ----
    // re-sentinel own chunk of slot (t+2)%3 (fire-and-forget; acked by next poll's vmcnt)
    if (l < 32) llc_st128(rdst_base + ((size_t)clr << 16), sentv);
    // delayed Hs store for step t-1 (HBM ack hides under compute, off the poll chain)
    if (t > 0 && l >= 32)
      *(f32x4*)(Hs + ((size_t)(rowbase + cl) * 511 + (t - 1)) * 512 + (g << 4) + cs * 8) = prevChunk;
    // tpos prefetch for step t+1 (consumed by next step's gates)
    float nf0[4], nf1[4], nf2[4];
    #pragma unroll
    for (int i = 0; i < 4; ++i) {
      const float* fp = tpos + ((size_t)(rowbase + (fh << 2) + i) * 512 + (t + 1)) * 3;
      nf0[i] = fp[0]; nf1[i] = fp[1]; nf2[i] = fp[2];
    }

    // MFMA: 6 independent chains of 8, then combine (prio 1: out-arbitrate spinning waves)
    __builtin_amdgcn_s_setprio(1);
    f32x4 x0 = {0.f,0.f,0.f,0.f}, x1 = {0.f,0.f,0.f,0.f}, x2 = {0.f,0.f,0.f,0.f};
    f32x4 y0 = {0.f,0.f,0.f,0.f}, y1 = {0.f,0.f,0.f,0.f}, y2 = {0.f,0.f,0.f,0.f};
#define GRU_STEP(A, KT, A0, A1, A2) { bf16x8 av = asbf(A); \
    A0 = __builtin_amdgcn_mfma_f32_16x16x32_bf16(av, wsm[(0*16+(KT))*64 + l].v, A0, 0, 0, 0); \
    A1 = __builtin_amdgcn_mfma_f32_16x16x32_bf16(av, wsm[(1*16+(KT))*64 + l].v, A1, 0, 0, 0); \
    A2 = __builtin_amdgcn_mfma_f32_16x16x32_bf16(av, wsm[(2*16+(KT))*64 + l].v, A2, 0, 0, 0); }
    GRU_STEP(a0,0,x0,x1,x2)   GRU_STEP(a8,8,y0,y1,y2)
    GRU_STEP(a1,1,x0,x1,x2)   GRU_STEP(a9,9,y0,y1,y2)
    GRU_STEP(a2,2,x0,x1,x2)   GRU_STEP(a10,10,y0,y1,y2)
    GRU_STEP(a3,3,x0,x1,x2)   GRU_STEP(a11,11,y0,y1,y2)
    GRU_STEP(a4,4,x0,x1,x2)   GRU_STEP(a12,12,y0,y1,y2)
    GRU_STEP(a5,5,x0,x1,x2)   GRU_STEP(a13,13,y0,y1,y2)
    GRU_STEP(a6,6,x0,x1,x2)   GRU_STEP(a14,14,y0,y1,y2)
    GRU_STEP(a7,7,x0,x1,x2)   GRU_STEP(a15,15,y0,y1,y2)
#undef GRU_STEP
    f32x4 acc0 = x0 + y0, acc1 = x1 + y1, acc2 = x2 + y2;

    // gates -> h2 -> LDS transpose tile (same-wave, no barrier); uses prefetched tpos(t)
    #pragma unroll
    for (int i = 0; i < 4; ++i) {
      float rr = sigm(cr + pf0[i] * Ar0 + pf1[i] * Ar1 + pf2[i] * Ar2 + acc0[i]);
      float uu = sigm(cu + pf0[i] * Au0 + pf1[i] * Au1 + pf2[i] * Au2 + acc1[i]);
      float nn = tanh_(cn + pf0[i] * An0 + pf1[i] * An1 + pf2[i] * An2 + rr * (acc2[i] + bhn));
      float h2 = (1.f - uu) * nn + uu * hprev[i];
      hprev[i] = h2;
      Tw[((fh << 2) + i) * 24 + fl] = f2b(h2);
    }
    __builtin_amdgcn_s_setprio(0);
    asm volatile("s_waitcnt lgkmcnt(0)" ::: "memory");
    __builtin_amdgcn_sched_barrier(0);

    f32x4 chunk = *(const f32x4*)(Tw + cl * 24 + cs * 8);   // row cl, units [16g+8cs, +8)
    if (l < 32) llc_st128(rdst_base + ((size_t)wr << 16), chunk);   // fire-and-forget
    prevChunk = chunk;
    #pragma unroll
    for (int i = 0; i < 4; ++i) { pf0[i] = nf0[i]; pf1[i] = nf1[i]; pf2[i] = nf2[i]; }
    cur = wr;
  }
  // epilogue: Hs store for the final step (t=510)
  if (l >= 32)
    *(f32x4*)(Hs + ((size_t)(rowbase + cl) * 511 + 510) * 512 + (g << 4) + cs * 8) = prevChunk;
}

// ---------------- FUSED: Q projection + attention/CE + mu/logvar/stop losses ----------------
__global__ __launch_bounds__(256) void k_qattn(
    const u16* __restrict__ Hs, const u16* __restrict__ wq, const float* __restrict__ bq,
    const u16* __restrict__ Kf, const int* __restrict__ parent,
    const float* __restrict__ tpos,
    const float* __restrict__ Wmu, const float* __restrict__ Wlv,
    const float* __restrict__ Ws, const float* __restrict__ bs,
    const float* __restrict__ Amu2, const float* __restrict__ cmu2,
    const float* __restrict__ Alv2, const float* __restrict__ clv2,
    float* __restrict__ out) {
  const int bid0 = blockIdx.x;                // XCD-swizzle: 4096 = 8 x 512
  const int bid = (bid0 & 7) * 512 + (bid0 >> 3);
  const int b = bid >> 5, mt = bid & 31;
  const int tid = threadIdx.x, w = tid >> 6, l = tid & 63;
  const int fl = l & 15, fh = l >> 4;
  __shared__ float qsm[16 * 516];
  __shared__ float sm_m[4][16], sm_s[4][16], sm_t[16];

  // ---- phase 1: Q projection (+ pos/stop dots on wave 0) ----
  const int t0 = mt * 16 + fl;
  const int tq = t0 > 510 ? 510 : t0;
  const u16* arow = Hs + ((size_t)b * 511 + tq) * 512 + fh * 8;
  f32x4 acc[8];
  #pragma unroll
  for (int p = 0; p < 8; ++p) acc[p] = (f32x4){0.f,0.f,0.f,0.f};
  float d0=0,d1=0,d2=0,d3=0,d4=0,d5=0,d6=0;
  for (int kt = 0; kt < 16; ++kt) {
    F16B a; a.f = *(const float4*)(arow + kt * 32);
    if (w == 0) {
      int c = kt * 32 + fh * 8;
      #pragma unroll
      for (int e = 0; e < 8; ++e) {
        float hv = b2f(a.u[e]);
        d0 += hv * Wmu[c+e]; d1 += hv * Wmu[1024+c+e]; d2 += hv * Wmu[2048+c+e];
        d3 += hv * Wlv[c+e]; d4 += hv * Wlv[1024+c+e]; d5 += hv * Wlv[2048+c+e];
        d6 += hv * Ws[c+e];
      }
    }
    #pragma unroll
    for (int p = 0; p < 8; ++p) {
      F16B bb; bb.f = *(const float4*)(wq + ((size_t)((w * 8 + p) * 16 + kt) * 64 + l) * 8);
      acc[p] = __builtin_amdgcn_mfma_f32_16x16x32_bf16(a.v, bb.v, acc[p], 0, 0, 0);
    }
  }
  if (w == 0) {
    d0 += __shfl_xor(d0, 16); d0 += __shfl_xor(d0, 32);
    d1 += __shfl_xor(d1, 16); d1 += __shfl_xor(d1, 32);
    d2 += __shfl_xor(d2, 16); d2 += __shfl_xor(d2, 32);
    d3 += __shfl_xor(d3, 16); d3 += __shfl_xor(d3, 32);
    d4 += __shfl_xor(d4, 16); d4 += __shfl_xor(d4, 32);
    d5 += __shfl_xor(d5, 16); d5 += __shfl_xor(d5, 32);
    d6 += __shfl_xor(d6, 16); d6 += __shfl_xor(d6, 32);
    if (fh == 0 && t0 < 511) {
      int tp = parent[b * 512 + t0 + 1];
      int ch = tp > 0 ? tp : 0;
      float p0 = 0.f, p1 = 0.f, p2 = 0.f;
      if (ch > 0) { const float* pp = tpos + ((size_t)b * 512 + ch) * 3; p0 = pp[0]; p1 = pp[1]; p2 = pp[2]; }
      const float* op = tpos + ((size_t)b * 512 + t0 + 1) * 3;
      float dm[3] = {d0, d1, d2}, dl[3] = {d3, d4, d5};
      float nll = 0.f;
      #pragma unroll
      for (int p = 0; p < 3; ++p) {
        float pc = (p == 0) ? p0 : (p == 1 ? p1 : p2);
        float mu = dm[p] + cmu2[p] + p0 * Amu2[p*4] + p1 * Amu2[p*4+1] + p2 * Amu2[p*4+2];
        float lv = dl[p] + clv2[p] + p0 * Alv2[p*4] + p1 * Alv2[p*4+1] + p2 * Alv2[p*4+2];
        float dd = (op[p] - pc) - mu;
        nll += 0.5f * (lv + dd * dd / (__expf(lv) + 1e-8f));
      }
      float sl = d6 + bs[0];
      float bce = (t0 == 510) ? splus(-sl) : splus(sl);
      atomicAdd(&out[b * 3 + 1], nll * (1.0f / 511.0f));
      atomicAdd(&out[b * 3 + 2], bce * (1.0f / 511.0f));
    }
  }
  #pragma unroll
  for (int p = 0; p < 8; ++p) {
    int n = (w * 8 + p) * 16 + fl;
    float add = bq[n];
    #pragma unroll
    for (int i = 0; i < 4; ++i)
      qsm[(fh * 4 + i) * 516 + n] = acc[p][i] + add;
  }
  __syncthreads();

  // ---- phase 2: attention scores + CE (A-fragments straight from qsm) ----
  f32x4 att[8];
  #pragma unroll
  for (int p = 0; p < 8; ++p) att[p] = (f32x4){0.f,0.f,0.f,0.f};
  for (int kt = 0; kt < 16; ++kt) {
    const float* src = &qsm[fl * 516 + kt * 32 + fh * 8];
    F16B a;
    #pragma unroll
    for (int e = 0; e < 8; ++e) a.u[e] = f2b(src[e]);
    #pragma unroll
    for (int p = 0; p < 8; ++p) {
      int nt = w + 4 * p;
      if (nt <= mt) {
        F16B bb; bb.f = *(const float4*)(Kf + (((size_t)(b * 32 + nt) * 16 + kt) * 64 + l) * 8);
        att[p] = __builtin_amdgcn_mfma_f32_16x16x32_bf16(a.v, bb.v, att[p], 0, 0, 0);
      }
    }
  }
  const float scale = 0.044194173824159216f;  // 1/sqrt(512)
  float S[8][4];
  float mrow[4] = {-3e38f, -3e38f, -3e38f, -3e38f};
  #pragma unroll
  for (int p = 0; p < 8; ++p) {
    int nt = w + 4 * p;
    int n = nt * 16 + fl;
    #pragma unroll
    for (int i = 0; i < 4; ++i) {
      int t = mt * 16 + fh * 4 + i;
      float s = -1e9f;
      if (nt <= mt && n <= t) s = att[p][i] * scale;
      S[p][i] = s;
      mrow[i] = fmaxf(mrow[i], s);
    }
  }
  #pragma unroll
  for (int i = 0; i < 4; ++i) {
    #pragma unroll
    for (int off = 1; off < 16; off <<= 1)
      mrow[i] = fmaxf(mrow[i], __shfl_xor(mrow[i], off, 64));
  }
  if (fl == 0) {
    #pragma unroll
    for (int i = 0; i < 4; ++i) sm_m[w][fh * 4 + i] = mrow[i];
  }
  __syncthreads();
  float M[4], esum[4];
  #pragma unroll
  for (int i = 0; i < 4; ++i) {
    int r = fh * 4 + i;
    M[i] = fmaxf(fmaxf(sm_m[0][r], sm_m[1][r]), fmaxf(sm_m[2][r], sm_m[3][r]));
    esum[i] = 0.f;
  }
  #pragma unroll
  for (int i = 0; i < 4; ++i) {
    int t = mt * 16 + fh * 4 + i;
    int tp = (t < 511) ? parent[b * 512 + t + 1] : -1;
    #pragma unroll
    for (int p = 0; p < 8; ++p) {
      int nt = w + 4 * p;
      int n = nt * 16 + fl;
      float e = (nt <= mt) ? __expf(S[p][i] - M[i]) : 0.f;
      esum[i] += e;
      if (nt <= mt && n == tp) sm_t[fh * 4 + i] = S[p][i];
    }
  }
  #pragma unroll
  for (int i = 0; i < 4; ++i) {
    #pragma unroll
    for (int off = 1; off < 16; off <<= 1)
      esum[i] += __shfl_xor(esum[i], off, 64);
  }
  if (fl == 0) {
    #pragma unroll
    for (int i = 0; i < 4; ++i) sm_s[w][fh * 4 + i] = esum[i];
  }
  __syncthreads();
  if (tid < 16) {
    int r = tid, t = mt * 16 + r;
    if (t < 511) {
      int tp = parent[b * 512 + t + 1];
      if (tp >= 0 && tp <= t) {
        float Mv = fmaxf(fmaxf(sm_m[0][r], sm_m[1][r]), fmaxf(sm_m[2][r], sm_m[3][r]));
        float Sv = sm_s[0][r] + sm_s[1][r] + sm_s[2][r] + sm_s[3][r];
        float ce = Mv + logf(Sv) - sm_t[r];
        atomicAdd(&out[b * 3 + 0], ce * (1.0f / 511.0f));
      }
    }
  }
}

extern "C" void kernel_launch(void* const* d_in, const int* in_sizes, int n_in,
                              void* d_out, int out_size, void* d_ws, size_t ws_size,
                              hipStream_t stream) {
  const float* z    = (const float*)d_in[0];
  const float* tpos = (const float*)d_in[1];
  const float* Wzh  = (const float*)d_in[2];
  const float* bzh  = (const float*)d_in[3];
  const float* Wne  = (const float*)d_in[4];
  const float* bne  = (const float*)d_in[5];
  const float* Wih  = (const float*)d_in[6];
  const float* bih  = (const float*)d_in[7];
  const float* Whh  = (const float*)d_in[8];
  const float* bhh  = (const float*)d_in[9];
  const float* Wq   = (const float*)d_in[10];
  const float* bq   = (const float*)d_in[11];
  const float* Wk   = (const float*)d_in[12];
  const float* bk   = (const float*)d_in[13];
  const float* Wmu  = (const float*)d_in[14];
  const float* bmu  = (const float*)d_in[15];
  const float* Wlv  = (const float*)d_in[16];
  const float* blv  = (const float*)d_in[17];
  const float* Ws   = (const float*)d_in[18];
  const float* bs   = (const float*)d_in[19];
  const int*   par  = (const int*)d_in[20];
  float* out = (float*)d_out;
  char* ws = (char*)d_ws;

  float* Aih   = (float*)(ws + OFF_AIH);
  float* cih   = (float*)(ws + OFF_CIH);
  float* Ak    = (float*)(ws + OFF_AK);
  float* ck    = (float*)(ws + OFF_CK);
  float* Amu2  = (float*)(ws + OFF_AMU2);
  float* cmu2  = (float*)(ws + OFF_CMU2);
  float* Alv2  = (float*)(ws + OFF_ALV2);
  float* clv2  = (float*)(ws + OFF_CLV2);
  u16*   ring  = (u16*)(ws + OFF_RING);
  u16*   whhf  = (u16*)(ws + OFF_WHH);
  u16*   wqf   = (u16*)(ws + OFF_WQ);
  u16*   Kf    = (u16*)(ws + OFF_KF);
  u16*   Hs    = (u16*)(ws + OFF_HS);
  (void)ws_size; (void)in_sizes; (void)n_in; (void)out_size;

  hipLaunchKernelGGL(k_zero,  dim3(64),    dim3(1024), 0, stream, out, (uint32_t*)ring);
  hipLaunchKernelGGL(k_fold,  dim3(41),    dim3(256), 0, stream, Wih, bih, Wk, bk, Wmu, bmu, Wlv, blv, Wne, bne,
                     Aih, cih, Ak, ck, Amu2, cmu2, Alv2, clv2);
  hipLaunchKernelGGL(k_h0,    dim3(32),    dim3(256), 0, stream, z, Wzh, bzh, ring);
  hipLaunchKernelGGL(k_wcvt,  dim3(128),   dim3(256), 0, stream, Wq, wqf, 32);
  hipLaunchKernelGGL(k_wcvt,  dim3(384),   dim3(256), 0, stream, Whh, whhf, 96);
  hipLaunchKernelGGL(k_kfrag, dim3(16384), dim3(256), 0, stream, tpos, Ak, ck, Kf);
  hipLaunchKernelGGL(k_gru,   dim3(64),    dim3(256), 0, stream, tpos, Aih, cih, bhh, whhf, ring, Hs);
  hipLaunchKernelGGL(k_qattn, dim3(4096),  dim3(256), 0, stream, Hs, wqf, bq, Kf, par, tpos,
                     Wmu, Wlv, Ws, bs, Amu2, cmu2, Alv2, clv2, out);
}

// Round 12
// 1998.997 us; speedup vs baseline: 1.1466x; 1.1466x over previous
//
#include <hip/hip_runtime.h>
#include <cstdint>
#include <cstddef>

typedef unsigned short u16;
typedef short bf16x8 __attribute__((ext_vector_type(8)));
typedef float f32x4 __attribute__((ext_vector_type(4)));

union F16B { float4 f; f32x4 fv; bf16x8 v; u16 u[8]; };
union U4 { f32x4 f; uint32_t u[4]; };

#define SENT 0x7FC07FC0u   // two bf16 NaNs; GRU h is tanh-bounded -> never NaN

__device__ __forceinline__ u16 f2b(float f) {
  uint32_t x = __float_as_uint(f);
  return (u16)((x + 0x7FFFu + ((x >> 16) & 1u)) >> 16);
}
__device__ __forceinline__ float b2f(u16 h) { return __uint_as_float(((uint32_t)h) << 16); }
__device__ __forceinline__ float sigm(float x) { return 1.0f / (1.0f + __expf(-x)); }
__device__ __forceinline__ float tanh_(float x) { return 1.0f - 2.0f / (__expf(2.0f * x) + 1.0f); }
__device__ __forceinline__ float splus(float x) { return logf(1.0f + __expf(x)); }
__device__ __forceinline__ bf16x8 asbf(f32x4 x) { F16B u; u.fv = x; return u.v; }
__device__ __forceinline__ uint32_t umin_(uint32_t a, uint32_t b) { return a < b ? a : b; }

__device__ __forceinline__ void llc_st128(u16* p, f32x4 v) {
  asm volatile("global_store_dwordx4 %0, %1, off sc0 sc1" :: "v"(p), "v"(v) : "memory");
}

// ---------------- sizes ----------------
// B=128 N=512 H=512 L=256 P=3 T=511
constexpr size_t OFF_AIH   = 32768;      // 1536*4 f32
constexpr size_t OFF_CIH   = 57344;      // 1536 f32
constexpr size_t OFF_AK    = 63488;      // 512*4 f32
constexpr size_t OFF_CK    = 71680;      // 512 f32
constexpr size_t OFF_AMU2  = 73728;
constexpr size_t OFF_CMU2  = 73792;
constexpr size_t OFF_ALV2  = 73856;
constexpr size_t OFF_CLV2  = 73920;
constexpr size_t OFF_WHH   = 336128;     // 1572864 B
constexpr size_t OFF_WQ    = 1908992;    // 524288 B
constexpr size_t OFF_KF    = 2433280;    // 67108864 B
constexpr size_t OFF_QF    = 69542144;   // (Qf eliminated by fusion; ring lives here)
constexpr size_t OFF_RING  = OFF_QF;     // 3 slots x 8rt x 16kt x 64 x 8 bf16 = 393216 B
constexpr size_t OFF_HS    = 136651008;  // 66977792 B

// ---------------- init: zero out, sentinel-fill ring slots 1,2 ----------------
__global__ void k_zero(float* out, uint32_t* ring32) {
  int tid = blockIdx.x * 1024 + threadIdx.x;   // grid 64 x 1024 = 65536
  if (tid < 384) out[tid] = 0.f;
  ring32[32768 + tid] = SENT;                  // dwords [32768,98304) = slots 1,2
}

// fold rank-4 matrices: A = W @ W_ne (rows x 4), c = b + W @ b_ne
__global__ void k_fold(const float* __restrict__ Wih, const float* __restrict__ bih,
                       const float* __restrict__ Wk,  const float* __restrict__ bk,
                       const float* __restrict__ Wmu, const float* __restrict__ bmu,
                       const float* __restrict__ Wlv, const float* __restrict__ blv,
                       const float* __restrict__ Wne, const float* __restrict__ bne,
                       float* Aih, float* cih, float* Ak, float* ck,
                       float* Amu2, float* cmu2, float* Alv2, float* clv2) {
  int tid = blockIdx.x * 256 + threadIdx.x;
  if (tid >= 2054 * 5) return;
  int row = tid / 5, c = tid % 5;
  const float* wrow; float bias; float* Adst; float* cdst;
  if (row < 1536)      { wrow = Wih + (size_t)row * 512;              bias = bih[row];      Adst = Aih  + row * 4;        cdst = cih  + row; }
  else if (row < 2048) { int j = row - 1536; wrow = Wk + (size_t)j * 512;       bias = bk[j];  Adst = Ak   + j * 4; cdst = ck   + j; }
  else if (row < 2051) { int j = row - 2048; wrow = Wmu + (size_t)j * 1024 + 512; bias = bmu[j]; Adst = Amu2 + j * 4; cdst = cmu2 + j; }
  else                 { int j = row - 2051; wrow = Wlv + (size_t)j * 1024 + 512; bias = blv[j]; Adst = Alv2 + j * 4; cdst = clv2 + j; }
  float acc = 0.f;
  if (c < 4) { for (int h = 0; h < 512; ++h) acc += wrow[h] * Wne[h * 4 + c]; Adst[c] = acc; }
  else       { for (int h = 0; h < 512; ++h) acc += wrow[h] * bne[h];         cdst[0] = bias + acc; }
}

// h0 = tanh(z @ Wzh^T + bzh) -> ring slot 0 in FRAGMENT layout
// ring[slot][rt][kt][lane][e] = h(row = rt*16 + (lane&15), unit = kt*32 + (lane>>4)*8 + e)
__global__ void k_h0(const float* __restrict__ z, const float* __restrict__ Wzh,
                     const float* __restrict__ bzh, u16* __restrict__ ring) {
  int tid = blockIdx.x * 256 + threadIdx.x;   // 8192 = 128 rows * 64 unit-groups
  int row = tid >> 6, ug = tid & 63;
  const float* zr = z + row * 256;
  F16B o;
  #pragma unroll
  for (int e = 0; e < 8; ++e) {
    int u = ug * 8 + e;
    float acc = bzh[u];
    const float* wr = Wzh + (size_t)u * 256;
    for (int k = 0; k < 256; ++k) acc += zr[k] * wr[k];
    o.u[e] = f2b(tanh_(acc));
  }
  int rt = row >> 4, kt = ug >> 2, sub = ug & 3;
  int lane = sub * 16 + (row & 15);
  *(float4*)(ring + (size_t)(((rt * 16 + kt) * 64 + lane) * 8)) = o.f;
}

// convert (rows x 512) f32 weight into MFMA B-fragment tile layout, bf16
__global__ void k_wcvt(const float* __restrict__ W, u16* __restrict__ dst, int ntiles) {
  int tid = blockIdx.x * 256 + threadIdx.x;
  if (tid >= ntiles * 1024) return;
  int rem = tid & 1023, l = rem & 63;
  int nt = tid >> 10, kt = rem >> 6;
  int row = nt * 16 + (l & 15);
  int kb = kt * 32 + (l >> 4) * 8;
  const float* src = W + (size_t)row * 512 + kb;
  F16B o;
  #pragma unroll
  for (int e = 0; e < 8; ++e) o.u[e] = f2b(src[e]);
  *(float4*)(dst + (size_t)tid * 8) = o.f;
}

// K fragments: Kf[b][nt][kt][lane][8] = K[b][n][k] with K = feat @ Ak^T + ck
__global__ void k_kfrag(const float* __restrict__ tpos, const float* __restrict__ Ak,
                        const float* __restrict__ ck, u16* __restrict__ Kf) {
  int tid = blockIdx.x * 256 + threadIdx.x;   // 128*32768
  int b = tid >> 15, rem = tid & 32767;
  int r2 = rem & 1023, l = r2 & 63;
  int nt = rem >> 10, kt = r2 >> 6;
  int n = nt * 16 + (l & 15);
  int kb = kt * 32 + (l >> 4) * 8;
  float f0 = 0.f, f1 = 0.f, f2 = 0.f;
  if (n > 0) { const float* fp = tpos + ((size_t)b * 512 + n) * 3; f0 = fp[0]; f1 = fp[1]; f2 = fp[2]; }
  F16B o;
  #pragma unroll
  for (int e = 0; e < 8; ++e) {
    int hh = kb + e;
    o.u[e] = f2b(ck[hh] + f0 * Ak[hh * 4] + f1 * Ak[hh * 4 + 1] + f2 * Ak[hh * 4 + 2]);
  }
  *(float4*)(Kf + (size_t)tid * 8) = o.f;
}

// ---------------- GRU: weight-stationary, sentinel-polled 3-slot ring, flag-free ----------------
// Round-9 proven body; single delta: s_sleep(8) backoff after each FAILED poll sweep
// (cuts coherent poll traffic ~40% to relieve LLC congestion; cannot affect correctness).
__global__ __launch_bounds__(256, 1) void k_gru(
    const float* __restrict__ tpos, const float* __restrict__ Aih, const float* __restrict__ cih,
    const float* __restrict__ bhh, const u16* __restrict__ whh,
    u16* __restrict__ ring, u16* __restrict__ Hs) {
  const int bid = blockIdx.x;
  const int half = bid & 1;
  const int g = bid >> 1;
  const int tid = threadIdx.x;
  const int w = tid >> 6;
  const int l = tid & 63;
  const int fl = l & 15, fh = l >> 4;
  __shared__ F16B wsm[3072];                    // 48 KB: 3 n-tiles x 16 k-tiles x 64 lanes
  __shared__ __align__(16) u16 trn[4][384];     // per-wave 16x16 transpose tile, stride 24 u16

  {
    const float4* src = (const float4*)whh;
    #pragma unroll
    for (int it = 0; it < 12; ++it) {
      int i = it * 256 + tid;               // 0..3071
      int ntl = i >> 10;
      int rem = i & 1023;
      int gnt = (ntl == 0) ? g : (ntl == 1 ? 32 + g : 64 + g);
      wsm[i].f = src[(size_t)gnt * 1024 + rem];
    }
  }
  const int jj = (g << 4) + fl;
  const float Ar0 = Aih[jj*4], Ar1 = Aih[jj*4+1], Ar2 = Aih[jj*4+2];
  const float Au0 = Aih[(512+jj)*4], Au1 = Aih[(512+jj)*4+1], Au2 = Aih[(512+jj)*4+2];
  const float An0 = Aih[(1024+jj)*4], An1 = Aih[(1024+jj)*4+1], An2 = Aih[(1024+jj)*4+2];
  const float cr = cih[jj] + bhh[jj];
  const float cu = cih[512+jj] + bhh[512+jj];
  const float cn = cih[1024+jj];
  const float bhn = bhh[1024+jj];
  const int rowbase = half * 64 + (w << 4);
  const int rt = (half << 2) + w;               // this wave's row-tile

  // hprev (this lane's 4 (row,unit) slots) from ring slot 0 fragment layout
  float hprev[4];
  {
    int kt_h = g >> 1;
    int sub_h = ((g & 1) << 1) | (fl >> 3);
    int e_h = fl & 7;
    #pragma unroll
    for (int i = 0; i < 4; ++i) {
      int lr = (fh << 2) + i;
      hprev[i] = b2f(ring[(size_t)(((rt * 16 + kt_h) * 64 + sub_h * 16 + lr) * 8 + e_h)]);
    }
  }
  // producer store mapping: chunk (cl=row-local, cs=8-unit-group)
  const int cl = fl;
  const int cs = fh & 1;
  u16* Tw = &trn[w][0];
  u16* rdst_base = ring + ((size_t)(rt * 16 + (g >> 1)) * 64 + ((((g & 1) << 1) | cs) * 16 + cl)) * 8;
  const u16* abase0 = ring + ((size_t)(rt * 16) * 64 + l) * 8;
  f32x4 sentv;
  sentv[0] = sentv[1] = sentv[2] = sentv[3] = __uint_as_float(SENT);
  __syncthreads();

  int cur = 0;                                  // slot holding h(t)
  for (int t = 0; t < 511; ++t) {
    int wr = cur + 1;  if (wr == 3) wr = 0;     // slot for h(t+1)
    int clr = wr + 1;  if (clr == 3) clr = 0;   // slot to re-sentinel (== (t+2)%3)

    // tpos loads for this step: in flight during the poll, drained by its vmcnt(0)
    float f0[4], f1[4], f2[4];
    #pragma unroll
    for (int i = 0; i < 4; ++i) {
      f0[i] = 0.f; f1[i] = 0.f; f2[i] = 0.f;
      if (t > 0) {
        const float* fp = tpos + ((size_t)(rowbase + (fh << 2) + i) * 512 + t) * 3;
        f0[i] = fp[0]; f1[i] = fp[1]; f2[i] = fp[2];
      }
    }

    // poll slot 'cur': 16 coherent 16B loads; ready when no dword is sentinel.
    // On success the fragments are ALREADY in registers (no separate load RT).
    const u16* b0 = abase0 + ((size_t)cur << 16);
    const u16* b1 = b0 + 2048;
    const u16* b2 = b0 + 4096;
    const u16* b3 = b0 + 6144;
    f32x4 a0,a1,a2,a3,a4,a5,a6,a7,a8,a9,a10,a11,a12,a13,a14,a15;
    while (true) {
      asm volatile(
        "global_load_dwordx4 %0, %16, off sc0 sc1\n\t"
        "global_load_dwordx4 %1, %16, off offset:1024 sc0 sc1\n\t"
        "global_load_dwordx4 %2, %16, off offset:2048 sc0 sc1\n\t"
        "global_load_dwordx4 %3, %16, off offset:3072 sc0 sc1\n\t"
        "global_load_dwordx4 %4, %17, off sc0 sc1\n\t"
        "global_load_dwordx4 %5, %17, off offset:1024 sc0 sc1\n\t"
        "global_load_dwordx4 %6, %17, off offset:2048 sc0 sc1\n\t"
        "global_load_dwordx4 %7, %17, off offset:3072 sc0 sc1\n\t"
        "global_load_dwordx4 %8, %18, off sc0 sc1\n\t"
        "global_load_dwordx4 %9, %18, off offset:1024 sc0 sc1\n\t"
        "global_load_dwordx4 %10, %18, off offset:2048 sc0 sc1\n\t"
        "global_load_dwordx4 %11, %18, off offset:3072 sc0 sc1\n\t"
        "global_load_dwordx4 %12, %19, off sc0 sc1\n\t"
        "global_load_dwordx4 %13, %19, off offset:1024 sc0 sc1\n\t"
        "global_load_dwordx4 %14, %19, off offset:2048 sc0 sc1\n\t"
        "global_load_dwordx4 %15, %19, off offset:3072 sc0 sc1\n\t"
        "s_waitcnt vmcnt(0)"
        : "=&v"(a0),"=&v"(a1),"=&v"(a2),"=&v"(a3),"=&v"(a4),"=&v"(a5),"=&v"(a6),"=&v"(a7),
          "=&v"(a8),"=&v"(a9),"=&v"(a10),"=&v"(a11),"=&v"(a12),"=&v"(a13),"=&v"(a14),"=&v"(a15)
        : "v"(b0),"v"(b1),"v"(b2),"v"(b3)
        : "memory");
      __builtin_amdgcn_sched_barrier(0);
      uint32_t mn = 0xFFFFFFFFu;
#define CHK(R) { U4 x; x.f = (R); \
      mn = umin_(mn, x.u[0]^SENT); mn = umin_(mn, x.u[1]^SENT); \
      mn = umin_(mn, x.u[2]^SENT); mn = umin_(mn, x.u[3]^SENT); }
      CHK(a0) CHK(a1) CHK(a2) CHK(a3) CHK(a4) CHK(a5) CHK(a6) CHK(a7)
      CHK(a8) CHK(a9) CHK(a10) CHK(a11) CHK(a12) CHK(a13) CHK(a14) CHK(a15)
#undef CHK
      if (__ballot(mn == 0u) == 0ull) break;
      __builtin_amdgcn_s_sleep(8);   // backoff: relieve LLC of coherent poll traffic
    }
    __builtin_amdgcn_sched_barrier(0);

    // re-sentinel own chunk of slot (t+2)%3 (fire-and-forget; acked by next poll's vmcnt)
    if (l < 32) llc_st128(rdst_base + ((size_t)clr << 16), sentv);

    // MFMA: 6 independent chains of 8, then combine
    f32x4 x0 = {0.f,0.f,0.f,0.f}, x1 = {0.f,0.f,0.f,0.f}, x2 = {0.f,0.f,0.f,0.f};
    f32x4 y0 = {0.f,0.f,0.f,0.f}, y1 = {0.f,0.f,0.f,0.f}, y2 = {0.f,0.f,0.f,0.f};
#define GRU_STEP(A, KT, A0, A1, A2) { bf16x8 av = asbf(A); \
    A0 = __builtin_amdgcn_mfma_f32_16x16x32_bf16(av, wsm[(0*16+(KT))*64 + l].v, A0, 0, 0, 0); \
    A1 = __builtin_amdgcn_mfma_f32_16x16x32_bf16(av, wsm[(1*16+(KT))*64 + l].v, A1, 0, 0, 0); \
    A2 = __builtin_amdgcn_mfma_f32_16x16x32_bf16(av, wsm[(2*16+(KT))*64 + l].v, A2, 0, 0, 0); }
    GRU_STEP(a0,0,x0,x1,x2)   GRU_STEP(a8,8,y0,y1,y2)
    GRU_STEP(a1,1,x0,x1,x2)   GRU_STEP(a9,9,y0,y1,y2)
    GRU_STEP(a2,2,x0,x1,x2)   GRU_STEP(a10,10,y0,y1,y2)
    GRU_STEP(a3,3,x0,x1,x2)   GRU_STEP(a11,11,y0,y1,y2)
    GRU_STEP(a4,4,x0,x1,x2)   GRU_STEP(a12,12,y0,y1,y2)
    GRU_STEP(a5,5,x0,x1,x2)   GRU_STEP(a13,13,y0,y1,y2)
    GRU_STEP(a6,6,x0,x1,x2)   GRU_STEP(a14,14,y0,y1,y2)
    GRU_STEP(a7,7,x0,x1,x2)   GRU_STEP(a15,15,y0,y1,y2)
#undef GRU_STEP
    f32x4 acc0 = x0 + y0, acc1 = x1 + y1, acc2 = x2 + y2;

    // gates -> h2 -> LDS transpose tile (same-wave, no barrier)
    #pragma unroll
    for (int i = 0; i < 4; ++i) {
      float rr = sigm(cr + f0[i] * Ar0 + f1[i] * Ar1 + f2[i] * Ar2 + acc0[i]);
      float uu = sigm(cu + f0[i] * Au0 + f1[i] * Au1 + f2[i] * Au2 + acc1[i]);
      float nn = tanh_(cn + f0[i] * An0 + f1[i] * An1 + f2[i] * An2 + rr * (acc2[i] + bhn));
      float h2 = (1.f - uu) * nn + uu * hprev[i];
      hprev[i] = h2;
      Tw[((fh << 2) + i) * 24 + fl] = f2b(h2);
    }
    asm volatile("s_waitcnt lgkmcnt(0)" ::: "memory");
    __builtin_amdgcn_sched_barrier(0);

    f32x4 chunk = *(const f32x4*)(Tw + cl * 24 + cs * 8);   // row cl, units [16g+8cs, +8)
    if (l < 32) llc_st128(rdst_base + ((size_t)wr << 16), chunk);   // fire-and-forget
    if (l >= 32)
      *(f32x4*)(Hs + ((size_t)(rowbase + cl) * 511 + t) * 512 + (g << 4) + cs * 8) = chunk;

    cur = wr;
  }
}

// ---------------- FUSED: Q projection + attention/CE + mu/logvar/stop losses ----------------
__global__ __launch_bounds__(256) void k_qattn(
    const u16* __restrict__ Hs, const u16* __restrict__ wq, const float* __restrict__ bq,
    const u16* __restrict__ Kf, const int* __restrict__ parent,
    const float* __restrict__ tpos,
    const float* __restrict__ Wmu, const float* __restrict__ Wlv,
    const float* __restrict__ Ws, const float* __restrict__ bs,
    const float* __restrict__ Amu2, const float* __restrict__ cmu2,
    const float* __restrict__ Alv2, const float* __restrict__ clv2,
    float* __restrict__ out) {
  const int bid0 = blockIdx.x;                // XCD-swizzle: 4096 = 8 x 512
  const int bid = (bid0 & 7) * 512 + (bid0 >> 3);
  const int b = bid >> 5, mt = bid & 31;
  const int tid = threadIdx.x, w = tid >> 6, l = tid & 63;
  const int fl = l & 15, fh = l >> 4;
  __shared__ float qsm[16 * 516];
  __shared__ float sm_m[4][16], sm_s[4][16], sm_t[16];

  // ---- phase 1: Q projection (+ pos/stop dots on wave 0) ----
  const int t0 = mt * 16 + fl;
  const int tq = t0 > 510 ? 510 : t0;
  const u16* arow = Hs + ((size_t)b * 511 + tq) * 512 + fh * 8;
  f32x4 acc[8];
  #pragma unroll
  for (int p = 0; p < 8; ++p) acc[p] = (f32x4){0.f,0.f,0.f,0.f};
  float d0=0,d1=0,d2=0,d3=0,d4=0,d5=0,d6=0;
  for (int kt = 0; kt < 16; ++kt) {
    F16B a; a.f = *(const float4*)(arow + kt * 32);
    if (w == 0) {
      int c = kt * 32 + fh * 8;
      #pragma unroll
      for (int e = 0; e < 8; ++e) {
        float hv = b2f(a.u[e]);
        d0 += hv * Wmu[c+e]; d1 += hv * Wmu[1024+c+e]; d2 += hv * Wmu[2048+c+e];
        d3 += hv * Wlv[c+e]; d4 += hv * Wlv[1024+c+e]; d5 += hv * Wlv[2048+c+e];
        d6 += hv * Ws[c+e];
      }
    }
    #pragma unroll
    for (int p = 0; p < 8; ++p) {
      F16B bb; bb.f = *(const float4*)(wq + ((size_t)((w * 8 + p) * 16 + kt) * 64 + l) * 8);
      acc[p] = __builtin_amdgcn_mfma_f32_16x16x32_bf16(a.v, bb.v, acc[p], 0, 0, 0);
    }
  }
  if (w == 0) {
    d0 += __shfl_xor(d0, 16); d0 += __shfl_xor(d0, 32);
    d1 += __shfl_xor(d1, 16); d1 += __shfl_xor(d1, 32);
    d2 += __shfl_xor(d2, 16); d2 += __shfl_xor(d2, 32);
    d3 += __shfl_xor(d3, 16); d3 += __shfl_xor(d3, 32);
    d4 += __shfl_xor(d4, 16); d4 += __shfl_xor(d4, 32);
    d5 += __shfl_xor(d5, 16); d5 += __shfl_xor(d5, 32);
    d6 += __shfl_xor(d6, 16); d6 += __shfl_xor(d6, 32);
    if (fh == 0 && t0 < 511) {
      int tp = parent[b * 512 + t0 + 1];
      int ch = tp > 0 ? tp : 0;
      float p0 = 0.f, p1 = 0.f, p2 = 0.f;
      if (ch > 0) { const float* pp = tpos + ((size_t)b * 512 + ch) * 3; p0 = pp[0]; p1 = pp[1]; p2 = pp[2]; }
      const float* op = tpos + ((size_t)b * 512 + t0 + 1) * 3;
      float dm[3] = {d0, d1, d2}, dl[3] = {d3, d4, d5};
      float nll = 0.f;
      #pragma unroll
      for (int p = 0; p < 3; ++p) {
        float pc = (p == 0) ? p0 : (p == 1 ? p1 : p2);
        float mu = dm[p] + cmu2[p] + p0 * Amu2[p*4] + p1 * Amu2[p*4+1] + p2 * Amu2[p*4+2];
        float lv = dl[p] + clv2[p] + p0 * Alv2[p*4] + p1 * Alv2[p*4+1] + p2 * Alv2[p*4+2];
        float dd = (op[p] - pc) - mu;
        nll += 0.5f * (lv + dd * dd / (__expf(lv) + 1e-8f));
      }
      float sl = d6 + bs[0];
      float bce = (t0 == 510) ? splus(-sl) : splus(sl);
      atomicAdd(&out[b * 3 + 1], nll * (1.0f / 511.0f));
      atomicAdd(&out[b * 3 + 2], bce * (1.0f / 511.0f));
    }
  }
  #pragma unroll
  for (int p = 0; p < 8; ++p) {
    int n = (w * 8 + p) * 16 + fl;
    float add = bq[n];
    #pragma unroll
    for (int i = 0; i < 4; ++i)
      qsm[(fh * 4 + i) * 516 + n] = acc[p][i] + add;
  }
  __syncthreads();

  // ---- phase 2: attention scores + CE (A-fragments straight from qsm) ----
  f32x4 att[8];
  #pragma unroll
  for (int p = 0; p < 8; ++p) att[p] = (f32x4){0.f,0.f,0.f,0.f};
  for (int kt = 0; kt < 16; ++kt) {
    const float* src = &qsm[fl * 516 + kt * 32 + fh * 8];
    F16B a;
    #pragma unroll
    for (int e = 0; e < 8; ++e) a.u[e] = f2b(src[e]);
    #pragma unroll
    for (int p = 0; p < 8; ++p) {
      int nt = w + 4 * p;
      if (nt <= mt) {
        F16B bb; bb.f = *(const float4*)(Kf + (((size_t)(b * 32 + nt) * 16 + kt) * 64 + l) * 8);
        att[p] = __builtin_amdgcn_mfma_f32_16x16x32_bf16(a.v, bb.v, att[p], 0, 0, 0);
      }
    }
  }
  const float scale = 0.044194173824159216f;  // 1/sqrt(512)
  float S[8][4];
  float mrow[4] = {-3e38f, -3e38f, -3e38f, -3e38f};
  #pragma unroll
  for (int p = 0; p < 8; ++p) {
    int nt = w + 4 * p;
    int n = nt * 16 + fl;
    #pragma unroll
    for (int i = 0; i < 4; ++i) {
      int t = mt * 16 + fh * 4 + i;
      float s = -1e9f;
      if (nt <= mt && n <= t) s = att[p][i] * scale;
      S[p][i] = s;
      mrow[i] = fmaxf(mrow[i], s);
    }
  }
  #pragma unroll
  for (int i = 0; i < 4; ++i) {
    #pragma unroll
    for (int off = 1; off < 16; off <<= 1)
      mrow[i] = fmaxf(mrow[i], __shfl_xor(mrow[i], off, 64));
  }
  if (fl == 0) {
    #pragma unroll
    for (int i = 0; i < 4; ++i) sm_m[w][fh * 4 + i] = mrow[i];
  }
  __syncthreads();
  float M[4], esum[4];
  #pragma unroll
  for (int i = 0; i < 4; ++i) {
    int r = fh * 4 + i;
    M[i] = fmaxf(fmaxf(sm_m[0][r], sm_m[1][r]), fmaxf(sm_m[2][r], sm_m[3][r]));
    esum[i] = 0.f;
  }
  #pragma unroll
  for (int i = 0; i < 4; ++i) {
    int t = mt * 16 + fh * 4 + i;
    int tp = (t < 511) ? parent[b * 512 + t + 1] : -1;
    #pragma unroll
    for (int p = 0; p < 8; ++p) {
      int nt = w + 4 * p;
      int n = nt * 16 + fl;
      float e = (nt <= mt) ? __expf(S[p][i] - M[i]) : 0.f;
      esum[i] += e;
      if (nt <= mt && n == tp) sm_t[fh * 4 + i] = S[p][i];
    }
  }
  #pragma unroll
  for (int i = 0; i < 4; ++i) {
    #pragma unroll
    for (int off = 1; off < 16; off <<= 1)
      esum[i] += __shfl_xor(esum[i], off, 64);
  }
  if (fl == 0) {
    #pragma unroll
    for (int i = 0; i < 4; ++i) sm_s[w][fh * 4 + i] = esum[i];
  }
  __syncthreads();
  if (tid < 16) {
    int r = tid, t = mt * 16 + r;
    if (t < 511) {
      int tp = parent[b * 512 + t + 1];
      if (tp >= 0 && tp <= t) {
        float Mv = fmaxf(fmaxf(sm_m[0][r], sm_m[1][r]), fmaxf(sm_m[2][r], sm_m[3][r]));
        float Sv = sm_s[0][r] + sm_s[1][r] + sm_s[2][r] + sm_s[3][r];
        float ce = Mv + logf(Sv) - sm_t[r];
        atomicAdd(&out[b * 3 + 0], ce * (1.0f / 511.0f));
      }
    }
  }
}

extern "C" void kernel_launch(void* const* d_in, const int* in_sizes, int n_in,
                              void* d_out, int out_size, void* d_ws, size_t ws_size,
                              hipStream_t stream) {
  const float* z    = (const float*)d_in[0];
  const float* tpos = (const float*)d_in[1];
  const float* Wzh  = (const float*)d_in[2];
  const float* bzh  = (const float*)d_in[3];
  const float* Wne  = (const float*)d_in[4];
  const float* bne  = (const float*)d_in[5];
  const float* Wih  = (const float*)d_in[6];
  const float* bih  = (const float*)d_in[7];
  const float* Whh  = (const float*)d_in[8];
  const float* bhh  = (const float*)d_in[9];
  const float* Wq   = (const float*)d_in[10];
  const float* bq   = (const float*)d_in[11];
  const float* Wk   = (const float*)d_in[12];
  const float* bk   = (const float*)d_in[13];
  const float* Wmu  = (const float*)d_in[14];
  const float* bmu  = (const float*)d_in[15];
  const float* Wlv  = (const float*)d_in[16];
  const float* blv  = (const float*)d_in[17];
  const float* Ws   = (const float*)d_in[18];
  const float* bs   = (const float*)d_in[19];
  const int*   par  = (const int*)d_in[20];
  float* out = (float*)d_out;
  char* ws = (char*)d_ws;

  float* Aih   = (float*)(ws + OFF_AIH);
  float* cih   = (float*)(ws + OFF_CIH);
  float* Ak    = (float*)(ws + OFF_AK);
  float* ck    = (float*)(ws + OFF_CK);
  float* Amu2  = (float*)(ws + OFF_AMU2);
  float* cmu2  = (float*)(ws + OFF_CMU2);
  float* Alv2  = (float*)(ws + OFF_ALV2);
  float* clv2  = (float*)(ws + OFF_CLV2);
  u16*   ring  = (u16*)(ws + OFF_RING);
  u16*   whhf  = (u16*)(ws + OFF_WHH);
  u16*   wqf   = (u16*)(ws + OFF_WQ);
  u16*   Kf    = (u16*)(ws + OFF_KF);
  u16*   Hs    = (u16*)(ws + OFF_HS);
  (void)ws_size; (void)in_sizes; (void)n_in; (void)out_size;

  hipLaunchKernelGGL(k_zero,  dim3(64),    dim3(1024), 0, stream, out, (uint32_t*)ring);
  hipLaunchKernelGGL(k_fold,  dim3(41),    dim3(256), 0, stream, Wih, bih, Wk, bk, Wmu, bmu, Wlv, blv, Wne, bne,
                     Aih, cih, Ak, ck, Amu2, cmu2, Alv2, clv2);
  hipLaunchKernelGGL(k_h0,    dim3(32),    dim3(256), 0, stream, z, Wzh, bzh, ring);
  hipLaunchKernelGGL(k_wcvt,  dim3(128),   dim3(256), 0, stream, Wq, wqf, 32);
  hipLaunchKernelGGL(k_wcvt,  dim3(384),   dim3(256), 0, stream, Whh, whhf, 96);
  hipLaunchKernelGGL(k_kfrag, dim3(16384), dim3(256), 0, stream, tpos, Ak, ck, Kf);
  hipLaunchKernelGGL(k_gru,   dim3(64),    dim3(256), 0, stream, tpos, Aih, cih, bhh, whhf, ring, Hs);
  hipLaunchKernelGGL(k_qattn, dim3(4096),  dim3(256), 0, stream, Hs, wqf, bq, Kf, par, tpos,
                     Wmu, Wlv, Ws, bs, Amu2, cmu2, Alv2, clv2, out);
}

// Round 13
// 1928.200 us; speedup vs baseline: 1.1887x; 1.0367x over previous
//
#include <hip/hip_runtime.h>
#include <cstdint>
#include <cstddef>

typedef unsigned short u16;
typedef short bf16x8 __attribute__((ext_vector_type(8)));
typedef float f32x4 __attribute__((ext_vector_type(4)));

union F16B { float4 f; f32x4 fv; bf16x8 v; u16 u[8]; };
union U4 { f32x4 f; uint32_t u[4]; };

#define SENT 0x7FC07FC0u   // two bf16 NaNs; GRU h is tanh-bounded -> never NaN

__device__ __forceinline__ u16 f2b(float f) {
  uint32_t x = __float_as_uint(f);
  return (u16)((x + 0x7FFFu + ((x >> 16) & 1u)) >> 16);
}
__device__ __forceinline__ float b2f(u16 h) { return __uint_as_float(((uint32_t)h) << 16); }
__device__ __forceinline__ float sigm(float x) { return 1.0f / (1.0f + __expf(-x)); }
__device__ __forceinline__ float tanh_(float x) { return 1.0f - 2.0f / (__expf(2.0f * x) + 1.0f); }
__device__ __forceinline__ float splus(float x) { return logf(1.0f + __expf(x)); }
__device__ __forceinline__ bf16x8 asbf(f32x4 x) { F16B u; u.fv = x; return u.v; }
__device__ __forceinline__ uint32_t umin_(uint32_t a, uint32_t b) { return a < b ? a : b; }

__device__ __forceinline__ void llc_st128(u16* p, f32x4 v) {
  asm volatile("global_store_dwordx4 %0, %1, off sc0 sc1" :: "v"(p), "v"(v) : "memory");
}

// ---------------- sizes ----------------
// B=128 N=512 H=512 L=256 P=3 T=511
constexpr size_t OFF_AIH   = 32768;      // 1536*4 f32
constexpr size_t OFF_CIH   = 57344;      // 1536 f32
constexpr size_t OFF_AK    = 63488;      // 512*4 f32
constexpr size_t OFF_CK    = 71680;      // 512 f32
constexpr size_t OFF_AMU2  = 73728;
constexpr size_t OFF_CMU2  = 73792;
constexpr size_t OFF_ALV2  = 73856;
constexpr size_t OFF_CLV2  = 73920;
constexpr size_t OFF_WHH   = 336128;     // 1572864 B
constexpr size_t OFF_WQ    = 1908992;    // 524288 B
constexpr size_t OFF_KF    = 2433280;    // 67108864 B
constexpr size_t OFF_QF    = 69542144;   // (Qf eliminated by fusion; ring lives here)
constexpr size_t OFF_RING  = OFF_QF;     // 3 slots x 8rt x 16kt x 64 x 8 bf16 = 393216 B
constexpr size_t OFF_HS    = 136651008;  // 66977792 B

// ---------------- init: zero out, sentinel-fill ring slots 1,2 ----------------
__global__ void k_zero(float* out, uint32_t* ring32) {
  int tid = blockIdx.x * 1024 + threadIdx.x;   // grid 64 x 1024 = 65536
  if (tid < 384) out[tid] = 0.f;
  ring32[32768 + tid] = SENT;                  // dwords [32768,98304) = slots 1,2
}

// fold rank-4 matrices: A = W @ W_ne (rows x 4), c = b + W @ b_ne
__global__ void k_fold(const float* __restrict__ Wih, const float* __restrict__ bih,
                       const float* __restrict__ Wk,  const float* __restrict__ bk,
                       const float* __restrict__ Wmu, const float* __restrict__ bmu,
                       const float* __restrict__ Wlv, const float* __restrict__ blv,
                       const float* __restrict__ Wne, const float* __restrict__ bne,
                       float* Aih, float* cih, float* Ak, float* ck,
                       float* Amu2, float* cmu2, float* Alv2, float* clv2) {
  int tid = blockIdx.x * 256 + threadIdx.x;
  if (tid >= 2054 * 5) return;
  int row = tid / 5, c = tid % 5;
  const float* wrow; float bias; float* Adst; float* cdst;
  if (row < 1536)      { wrow = Wih + (size_t)row * 512;              bias = bih[row];      Adst = Aih  + row * 4;        cdst = cih  + row; }
  else if (row < 2048) { int j = row - 1536; wrow = Wk + (size_t)j * 512;       bias = bk[j];  Adst = Ak   + j * 4; cdst = ck   + j; }
  else if (row < 2051) { int j = row - 2048; wrow = Wmu + (size_t)j * 1024 + 512; bias = bmu[j]; Adst = Amu2 + j * 4; cdst = cmu2 + j; }
  else                 { int j = row - 2051; wrow = Wlv + (size_t)j * 1024 + 512; bias = blv[j]; Adst = Alv2 + j * 4; cdst = clv2 + j; }
  float acc = 0.f;
  if (c < 4) { for (int h = 0; h < 512; ++h) acc += wrow[h] * Wne[h * 4 + c]; Adst[c] = acc; }
  else       { for (int h = 0; h < 512; ++h) acc += wrow[h] * bne[h];         cdst[0] = bias + acc; }
}

// h0 = tanh(z @ Wzh^T + bzh) -> ring slot 0 in FRAGMENT layout
// ring[slot][rt][kt][lane][e] = h(row = rt*16 + (lane&15), unit = kt*32 + (lane>>4)*8 + e)
__global__ void k_h0(const float* __restrict__ z, const float* __restrict__ Wzh,
                     const float* __restrict__ bzh, u16* __restrict__ ring) {
  int tid = blockIdx.x * 256 + threadIdx.x;   // 8192 = 128 rows * 64 unit-groups
  int row = tid >> 6, ug = tid & 63;
  const float* zr = z + row * 256;
  F16B o;
  #pragma unroll
  for (int e = 0; e < 8; ++e) {
    int u = ug * 8 + e;
    float acc = bzh[u];
    const float* wr = Wzh + (size_t)u * 256;
    for (int k = 0; k < 256; ++k) acc += zr[k] * wr[k];
    o.u[e] = f2b(tanh_(acc));
  }
  int rt = row >> 4, kt = ug >> 2, sub = ug & 3;
  int lane = sub * 16 + (row & 15);
  *(float4*)(ring + (size_t)(((rt * 16 + kt) * 64 + lane) * 8)) = o.f;
}

// convert (rows x 512) f32 weight into MFMA B-fragment tile layout, bf16
__global__ void k_wcvt(const float* __restrict__ W, u16* __restrict__ dst, int ntiles) {
  int tid = blockIdx.x * 256 + threadIdx.x;
  if (tid >= ntiles * 1024) return;
  int rem = tid & 1023, l = rem & 63;
  int nt = tid >> 10, kt = rem >> 6;
  int row = nt * 16 + (l & 15);
  int kb = kt * 32 + (l >> 4) * 8;
  const float* src = W + (size_t)row * 512 + kb;
  F16B o;
  #pragma unroll
  for (int e = 0; e < 8; ++e) o.u[e] = f2b(src[e]);
  *(float4*)(dst + (size_t)tid * 8) = o.f;
}

// K fragments: Kf[b][nt][kt][lane][8] = K[b][n][k] with K = feat @ Ak^T + ck
__global__ void k_kfrag(const float* __restrict__ tpos, const float* __restrict__ Ak,
                        const float* __restrict__ ck, u16* __restrict__ Kf) {
  int tid = blockIdx.x * 256 + threadIdx.x;   // 128*32768
  int b = tid >> 15, rem = tid & 32767;
  int r2 = rem & 1023, l = r2 & 63;
  int nt = rem >> 10, kt = r2 >> 6;
  int n = nt * 16 + (l & 15);
  int kb = kt * 32 + (l >> 4) * 8;
  float f0 = 0.f, f1 = 0.f, f2 = 0.f;
  if (n > 0) { const float* fp = tpos + ((size_t)b * 512 + n) * 3; f0 = fp[0]; f1 = fp[1]; f2 = fp[2]; }
  F16B o;
  #pragma unroll
  for (int e = 0; e < 8; ++e) {
    int hh = kb + e;
    o.u[e] = f2b(ck[hh] + f0 * Ak[hh * 4] + f1 * Ak[hh * 4 + 1] + f2 * Ak[hh * 4 + 2]);
  }
  *(float4*)(Kf + (size_t)tid * 8) = o.f;
}

// ---------------- GRU: weight-stationary, sentinel-polled 3-slot ring, flag-free ----------------
// (round-9 proven version, verbatim — best measured configuration)
__global__ __launch_bounds__(256, 1) void k_gru(
    const float* __restrict__ tpos, const float* __restrict__ Aih, const float* __restrict__ cih,
    const float* __restrict__ bhh, const u16* __restrict__ whh,
    u16* __restrict__ ring, u16* __restrict__ Hs) {
  const int bid = blockIdx.x;
  const int half = bid & 1;
  const int g = bid >> 1;
  const int tid = threadIdx.x;
  const int w = tid >> 6;
  const int l = tid & 63;
  const int fl = l & 15, fh = l >> 4;
  __shared__ F16B wsm[3072];                    // 48 KB: 3 n-tiles x 16 k-tiles x 64 lanes
  __shared__ __align__(16) u16 trn[4][384];     // per-wave 16x16 transpose tile, stride 24 u16

  {
    const float4* src = (const float4*)whh;
    #pragma unroll
    for (int it = 0; it < 12; ++it) {
      int i = it * 256 + tid;               // 0..3071
      int ntl = i >> 10;
      int rem = i & 1023;
      int gnt = (ntl == 0) ? g : (ntl == 1 ? 32 + g : 64 + g);
      wsm[i].f = src[(size_t)gnt * 1024 + rem];
    }
  }
  const int jj = (g << 4) + fl;
  const float Ar0 = Aih[jj*4], Ar1 = Aih[jj*4+1], Ar2 = Aih[jj*4+2];
  const float Au0 = Aih[(512+jj)*4], Au1 = Aih[(512+jj)*4+1], Au2 = Aih[(512+jj)*4+2];
  const float An0 = Aih[(1024+jj)*4], An1 = Aih[(1024+jj)*4+1], An2 = Aih[(1024+jj)*4+2];
  const float cr = cih[jj] + bhh[jj];
  const float cu = cih[512+jj] + bhh[512+jj];
  const float cn = cih[1024+jj];
  const float bhn = bhh[1024+jj];
  const int rowbase = half * 64 + (w << 4);
  const int rt = (half << 2) + w;               // this wave's row-tile

  // hprev (this lane's 4 (row,unit) slots) from ring slot 0 fragment layout
  float hprev[4];
  {
    int kt_h = g >> 1;
    int sub_h = ((g & 1) << 1) | (fl >> 3);
    int e_h = fl & 7;
    #pragma unroll
    for (int i = 0; i < 4; ++i) {
      int lr = (fh << 2) + i;
      hprev[i] = b2f(ring[(size_t)(((rt * 16 + kt_h) * 64 + sub_h * 16 + lr) * 8 + e_h)]);
    }
  }
  // producer store mapping: chunk (cl=row-local, cs=8-unit-group)
  const int cl = fl;
  const int cs = fh & 1;
  u16* Tw = &trn[w][0];
  u16* rdst_base = ring + ((size_t)(rt * 16 + (g >> 1)) * 64 + ((((g & 1) << 1) | cs) * 16 + cl)) * 8;
  const u16* abase0 = ring + ((size_t)(rt * 16) * 64 + l) * 8;
  f32x4 sentv;
  sentv[0] = sentv[1] = sentv[2] = sentv[3] = __uint_as_float(SENT);
  __syncthreads();

  int cur = 0;                                  // slot holding h(t)
  for (int t = 0; t < 511; ++t) {
    int wr = cur + 1;  if (wr == 3) wr = 0;     // slot for h(t+1)
    int clr = wr + 1;  if (clr == 3) clr = 0;   // slot to re-sentinel (== (t+2)%3)

    // tpos loads for this step: in flight during the poll, drained by its vmcnt(0)
    float f0[4], f1[4], f2[4];
    #pragma unroll
    for (int i = 0; i < 4; ++i) {
      f0[i] = 0.f; f1[i] = 0.f; f2[i] = 0.f;
      if (t > 0) {
        const float* fp = tpos + ((size_t)(rowbase + (fh << 2) + i) * 512 + t) * 3;
        f0[i] = fp[0]; f1[i] = fp[1]; f2[i] = fp[2];
      }
    }

    // poll slot 'cur': 16 coherent 16B loads; ready when no dword is sentinel.
    // On success the fragments are ALREADY in registers (no separate load RT).
    const u16* b0 = abase0 + ((size_t)cur << 16);
    const u16* b1 = b0 + 2048;
    const u16* b2 = b0 + 4096;
    const u16* b3 = b0 + 6144;
    f32x4 a0,a1,a2,a3,a4,a5,a6,a7,a8,a9,a10,a11,a12,a13,a14,a15;
    while (true) {
      asm volatile(
        "global_load_dwordx4 %0, %16, off sc0 sc1\n\t"
        "global_load_dwordx4 %1, %16, off offset:1024 sc0 sc1\n\t"
        "global_load_dwordx4 %2, %16, off offset:2048 sc0 sc1\n\t"
        "global_load_dwordx4 %3, %16, off offset:3072 sc0 sc1\n\t"
        "global_load_dwordx4 %4, %17, off sc0 sc1\n\t"
        "global_load_dwordx4 %5, %17, off offset:1024 sc0 sc1\n\t"
        "global_load_dwordx4 %6, %17, off offset:2048 sc0 sc1\n\t"
        "global_load_dwordx4 %7, %17, off offset:3072 sc0 sc1\n\t"
        "global_load_dwordx4 %8, %18, off sc0 sc1\n\t"
        "global_load_dwordx4 %9, %18, off offset:1024 sc0 sc1\n\t"
        "global_load_dwordx4 %10, %18, off offset:2048 sc0 sc1\n\t"
        "global_load_dwordx4 %11, %18, off offset:3072 sc0 sc1\n\t"
        "global_load_dwordx4 %12, %19, off sc0 sc1\n\t"
        "global_load_dwordx4 %13, %19, off offset:1024 sc0 sc1\n\t"
        "global_load_dwordx4 %14, %19, off offset:2048 sc0 sc1\n\t"
        "global_load_dwordx4 %15, %19, off offset:3072 sc0 sc1\n\t"
        "s_waitcnt vmcnt(0)"
        : "=&v"(a0),"=&v"(a1),"=&v"(a2),"=&v"(a3),"=&v"(a4),"=&v"(a5),"=&v"(a6),"=&v"(a7),
          "=&v"(a8),"=&v"(a9),"=&v"(a10),"=&v"(a11),"=&v"(a12),"=&v"(a13),"=&v"(a14),"=&v"(a15)
        : "v"(b0),"v"(b1),"v"(b2),"v"(b3)
        : "memory");
      __builtin_amdgcn_sched_barrier(0);
      uint32_t mn = 0xFFFFFFFFu;
#define CHK(R) { U4 x; x.f = (R); \
      mn = umin_(mn, x.u[0]^SENT); mn = umin_(mn, x.u[1]^SENT); \
      mn = umin_(mn, x.u[2]^SENT); mn = umin_(mn, x.u[3]^SENT); }
      CHK(a0) CHK(a1) CHK(a2) CHK(a3) CHK(a4) CHK(a5) CHK(a6) CHK(a7)
      CHK(a8) CHK(a9) CHK(a10) CHK(a11) CHK(a12) CHK(a13) CHK(a14) CHK(a15)
#undef CHK
      if (__ballot(mn == 0u) == 0ull) break;
    }
    __builtin_amdgcn_sched_barrier(0);

    // re-sentinel own chunk of slot (t+2)%3 (fire-and-forget; acked by next poll's vmcnt)
    if (l < 32) llc_st128(rdst_base + ((size_t)clr << 16), sentv);

    // MFMA: 6 independent chains of 8, then combine
    f32x4 x0 = {0.f,0.f,0.f,0.f}, x1 = {0.f,0.f,0.f,0.f}, x2 = {0.f,0.f,0.f,0.f};
    f32x4 y0 = {0.f,0.f,0.f,0.f}, y1 = {0.f,0.f,0.f,0.f}, y2 = {0.f,0.f,0.f,0.f};
#define GRU_STEP(A, KT, A0, A1, A2) { bf16x8 av = asbf(A); \
    A0 = __builtin_amdgcn_mfma_f32_16x16x32_bf16(av, wsm[(0*16+(KT))*64 + l].v, A0, 0, 0, 0); \
    A1 = __builtin_amdgcn_mfma_f32_16x16x32_bf16(av, wsm[(1*16+(KT))*64 + l].v, A1, 0, 0, 0); \
    A2 = __builtin_amdgcn_mfma_f32_16x16x32_bf16(av, wsm[(2*16+(KT))*64 + l].v, A2, 0, 0, 0); }
    GRU_STEP(a0,0,x0,x1,x2)   GRU_STEP(a8,8,y0,y1,y2)
    GRU_STEP(a1,1,x0,x1,x2)   GRU_STEP(a9,9,y0,y1,y2)
    GRU_STEP(a2,2,x0,x1,x2)   GRU_STEP(a10,10,y0,y1,y2)
    GRU_STEP(a3,3,x0,x1,x2)   GRU_STEP(a11,11,y0,y1,y2)
    GRU_STEP(a4,4,x0,x1,x2)   GRU_STEP(a12,12,y0,y1,y2)
    GRU_STEP(a5,5,x0,x1,x2)   GRU_STEP(a13,13,y0,y1,y2)
    GRU_STEP(a6,6,x0,x1,x2)   GRU_STEP(a14,14,y0,y1,y2)
    GRU_STEP(a7,7,x0,x1,x2)   GRU_STEP(a15,15,y0,y1,y2)
#undef GRU_STEP
    f32x4 acc0 = x0 + y0, acc1 = x1 + y1, acc2 = x2 + y2;

    // gates -> h2 -> LDS transpose tile (same-wave, no barrier)
    #pragma unroll
    for (int i = 0; i < 4; ++i) {
      float rr = sigm(cr + f0[i] * Ar0 + f1[i] * Ar1 + f2[i] * Ar2 + acc0[i]);
      float uu = sigm(cu + f0[i] * Au0 + f1[i] * Au1 + f2[i] * Au2 + acc1[i]);
      float nn = tanh_(cn + f0[i] * An0 + f1[i] * An1 + f2[i] * An2 + rr * (acc2[i] + bhn));
      float h2 = (1.f - uu) * nn + uu * hprev[i];
      hprev[i] = h2;
      Tw[((fh << 2) + i) * 24 + fl] = f2b(h2);
    }
    asm volatile("s_waitcnt lgkmcnt(0)" ::: "memory");
    __builtin_amdgcn_sched_barrier(0);

    f32x4 chunk = *(const f32x4*)(Tw + cl * 24 + cs * 8);   // row cl, units [16g+8cs, +8)
    if (l < 32) llc_st128(rdst_base + ((size_t)wr << 16), chunk);   // fire-and-forget
    if (l >= 32)
      *(f32x4*)(Hs + ((size_t)(rowbase + cl) * 511 + t) * 512 + (g << 4) + cs * 8) = chunk;

    cur = wr;
  }
}

// ---------------- FUSED: Q projection + attention/CE + mu/logvar/stop losses ----------------
__global__ __launch_bounds__(256) void k_qattn(
    const u16* __restrict__ Hs, const u16* __restrict__ wq, const float* __restrict__ bq,
    const u16* __restrict__ Kf, const int* __restrict__ parent,
    const float* __restrict__ tpos,
    const float* __restrict__ Wmu, const float* __restrict__ Wlv,
    const float* __restrict__ Ws, const float* __restrict__ bs,
    const float* __restrict__ Amu2, const float* __restrict__ cmu2,
    const float* __restrict__ Alv2, const float* __restrict__ clv2,
    float* __restrict__ out) {
  const int bid0 = blockIdx.x;                // XCD-swizzle: 4096 = 8 x 512
  const int bid = (bid0 & 7) * 512 + (bid0 >> 3);
  const int b = bid >> 5, mt = bid & 31;
  const int tid = threadIdx.x, w = tid >> 6, l = tid & 63;
  const int fl = l & 15, fh = l >> 4;
  __shared__ float qsm[16 * 516];
  __shared__ float sm_m[4][16], sm_s[4][16], sm_t[16];

  // ---- phase 1: Q projection (+ pos/stop dots on wave 0) ----
  const int t0 = mt * 16 + fl;
  const int tq = t0 > 510 ? 510 : t0;
  const u16* arow = Hs + ((size_t)b * 511 + tq) * 512 + fh * 8;
  f32x4 acc[8];
  #pragma unroll
  for (int p = 0; p < 8; ++p) acc[p] = (f32x4){0.f,0.f,0.f,0.f};
  float d0=0,d1=0,d2=0,d3=0,d4=0,d5=0,d6=0;
  for (int kt = 0; kt < 16; ++kt) {
    F16B a; a.f = *(const float4*)(arow + kt * 32);
    if (w == 0) {
      int c = kt * 32 + fh * 8;
      #pragma unroll
      for (int e = 0; e < 8; ++e) {
        float hv = b2f(a.u[e]);
        d0 += hv * Wmu[c+e]; d1 += hv * Wmu[1024+c+e]; d2 += hv * Wmu[2048+c+e];
        d3 += hv * Wlv[c+e]; d4 += hv * Wlv[1024+c+e]; d5 += hv * Wlv[2048+c+e];
        d6 += hv * Ws[c+e];
      }
    }
    #pragma unroll
    for (int p = 0; p < 8; ++p) {
      F16B bb; bb.f = *(const float4*)(wq + ((size_t)((w * 8 + p) * 16 + kt) * 64 + l) * 8);
      acc[p] = __builtin_amdgcn_mfma_f32_16x16x32_bf16(a.v, bb.v, acc[p], 0, 0, 0);
    }
  }
  if (w == 0) {
    d0 += __shfl_xor(d0, 16); d0 += __shfl_xor(d0, 32);
    d1 += __shfl_xor(d1, 16); d1 += __shfl_xor(d1, 32);
    d2 += __shfl_xor(d2, 16); d2 += __shfl_xor(d2, 32);
    d3 += __shfl_xor(d3, 16); d3 += __shfl_xor(d3, 32);
    d4 += __shfl_xor(d4, 16); d4 += __shfl_xor(d4, 32);
    d5 += __shfl_xor(d5, 16); d5 += __shfl_xor(d5, 32);
    d6 += __shfl_xor(d6, 16); d6 += __shfl_xor(d6, 32);
    if (fh == 0 && t0 < 511) {
      int tp = parent[b * 512 + t0 + 1];
      int ch = tp > 0 ? tp : 0;
      float p0 = 0.f, p1 = 0.f, p2 = 0.f;
      if (ch > 0) { const float* pp = tpos + ((size_t)b * 512 + ch) * 3; p0 = pp[0]; p1 = pp[1]; p2 = pp[2]; }
      const float* op = tpos + ((size_t)b * 512 + t0 + 1) * 3;
      float dm[3] = {d0, d1, d2}, dl[3] = {d3, d4, d5};
      float nll = 0.f;
      #pragma unroll
      for (int p = 0; p < 3; ++p) {
        float pc = (p == 0) ? p0 : (p == 1 ? p1 : p2);
        float mu = dm[p] + cmu2[p] + p0 * Amu2[p*4] + p1 * Amu2[p*4+1] + p2 * Amu2[p*4+2];
        float lv = dl[p] + clv2[p] + p0 * Alv2[p*4] + p1 * Alv2[p*4+1] + p2 * Alv2[p*4+2];
        float dd = (op[p] - pc) - mu;
        nll += 0.5f * (lv + dd * dd / (__expf(lv) + 1e-8f));
      }
      float sl = d6 + bs[0];
      float bce = (t0 == 510) ? splus(-sl) : splus(sl);
      atomicAdd(&out[b * 3 + 1], nll * (1.0f / 511.0f));
      atomicAdd(&out[b * 3 + 2], bce * (1.0f / 511.0f));
    }
  }
  #pragma unroll
  for (int p = 0; p < 8; ++p) {
    int n = (w * 8 + p) * 16 + fl;
    float add = bq[n];
    #pragma unroll
    for (int i = 0; i < 4; ++i)
      qsm[(fh * 4 + i) * 516 + n] = acc[p][i] + add;
  }
  __syncthreads();

  // ---- phase 2: attention scores + CE (A-fragments straight from qsm) ----
  f32x4 att[8];
  #pragma unroll
  for (int p = 0; p < 8; ++p) att[p] = (f32x4){0.f,0.f,0.f,0.f};
  for (int kt = 0; kt < 16; ++kt) {
    const float* src = &qsm[fl * 516 + kt * 32 + fh * 8];
    F16B a;
    #pragma unroll
    for (int e = 0; e < 8; ++e) a.u[e] = f2b(src[e]);
    #pragma unroll
    for (int p = 0; p < 8; ++p) {
      int nt = w + 4 * p;
      if (nt <= mt) {
        F16B bb; bb.f = *(const float4*)(Kf + (((size_t)(b * 32 + nt) * 16 + kt) * 64 + l) * 8);
        att[p] = __builtin_amdgcn_mfma_f32_16x16x32_bf16(a.v, bb.v, att[p], 0, 0, 0);
      }
    }
  }
  const float scale = 0.044194173824159216f;  // 1/sqrt(512)
  float S[8][4];
  float mrow[4] = {-3e38f, -3e38f, -3e38f, -3e38f};
  #pragma unroll
  for (int p = 0; p < 8; ++p) {
    int nt = w + 4 * p;
    int n = nt * 16 + fl;
    #pragma unroll
    for (int i = 0; i < 4; ++i) {
      int t = mt * 16 + fh * 4 + i;
      float s = -1e9f;
      if (nt <= mt && n <= t) s = att[p][i] * scale;
      S[p][i] = s;
      mrow[i] = fmaxf(mrow[i], s);
    }
  }
  #pragma unroll
  for (int i = 0; i < 4; ++i) {
    #pragma unroll
    for (int off = 1; off < 16; off <<= 1)
      mrow[i] = fmaxf(mrow[i], __shfl_xor(mrow[i], off, 64));
  }
  if (fl == 0) {
    #pragma unroll
    for (int i = 0; i < 4; ++i) sm_m[w][fh * 4 + i] = mrow[i];
  }
  __syncthreads();
  float M[4], esum[4];
  #pragma unroll
  for (int i = 0; i < 4; ++i) {
    int r = fh * 4 + i;
    M[i] = fmaxf(fmaxf(sm_m[0][r], sm_m[1][r]), fmaxf(sm_m[2][r], sm_m[3][r]));
    esum[i] = 0.f;
  }
  #pragma unroll
  for (int i = 0; i < 4; ++i) {
    int t = mt * 16 + fh * 4 + i;
    int tp = (t < 511) ? parent[b * 512 + t + 1] : -1;
    #pragma unroll
    for (int p = 0; p < 8; ++p) {
      int nt = w + 4 * p;
      int n = nt * 16 + fl;
      float e = (nt <= mt) ? __expf(S[p][i] - M[i]) : 0.f;
      esum[i] += e;
      if (nt <= mt && n == tp) sm_t[fh * 4 + i] = S[p][i];
    }
  }
  #pragma unroll
  for (int i = 0; i < 4; ++i) {
    #pragma unroll
    for (int off = 1; off < 16; off <<= 1)
      esum[i] += __shfl_xor(esum[i], off, 64);
  }
  if (fl == 0) {
    #pragma unroll
    for (int i = 0; i < 4; ++i) sm_s[w][fh * 4 + i] = esum[i];
  }
  __syncthreads();
  if (tid < 16) {
    int r = tid, t = mt * 16 + r;
    if (t < 511) {
      int tp = parent[b * 512 + t + 1];
      if (tp >= 0 && tp <= t) {
        float Mv = fmaxf(fmaxf(sm_m[0][r], sm_m[1][r]), fmaxf(sm_m[2][r], sm_m[3][r]));
        float Sv = sm_s[0][r] + sm_s[1][r] + sm_s[2][r] + sm_s[3][r];
        float ce = Mv + logf(Sv) - sm_t[r];
        atomicAdd(&out[b * 3 + 0], ce * (1.0f / 511.0f));
      }
    }
  }
}

extern "C" void kernel_launch(void* const* d_in, const int* in_sizes, int n_in,
                              void* d_out, int out_size, void* d_ws, size_t ws_size,
                              hipStream_t stream) {
  const float* z    = (const float*)d_in[0];
  const float* tpos = (const float*)d_in[1];
  const float* Wzh  = (const float*)d_in[2];
  const float* bzh  = (const float*)d_in[3];
  const float* Wne  = (const float*)d_in[4];
  const float* bne  = (const float*)d_in[5];
  const float* Wih  = (const float*)d_in[6];
  const float* bih  = (const float*)d_in[7];
  const float* Whh  = (const float*)d_in[8];
  const float* bhh  = (const float*)d_in[9];
  const float* Wq   = (const float*)d_in[10];
  const float* bq   = (const float*)d_in[11];
  const float* Wk   = (const float*)d_in[12];
  const float* bk   = (const float*)d_in[13];
  const float* Wmu  = (const float*)d_in[14];
  const float* bmu  = (const float*)d_in[15];
  const float* Wlv  = (const float*)d_in[16];
  const float* blv  = (const float*)d_in[17];
  const float* Ws   = (const float*)d_in[18];
  const float* bs   = (const float*)d_in[19];
  const int*   par  = (const int*)d_in[20];
  float* out = (float*)d_out;
  char* ws = (char*)d_ws;

  float* Aih   = (float*)(ws + OFF_AIH);
  float* cih   = (float*)(ws + OFF_CIH);
  float* Ak    = (float*)(ws + OFF_AK);
  float* ck    = (float*)(ws + OFF_CK);
  float* Amu2  = (float*)(ws + OFF_AMU2);
  float* cmu2  = (float*)(ws + OFF_CMU2);
  float* Alv2  = (float*)(ws + OFF_ALV2);
  float* clv2  = (float*)(ws + OFF_CLV2);
  u16*   ring  = (u16*)(ws + OFF_RING);
  u16*   whhf  = (u16*)(ws + OFF_WHH);
  u16*   wqf   = (u16*)(ws + OFF_WQ);
  u16*   Kf    = (u16*)(ws + OFF_KF);
  u16*   Hs    = (u16*)(ws + OFF_HS);
  (void)ws_size; (void)in_sizes; (void)n_in; (void)out_size;

  hipLaunchKernelGGL(k_zero,  dim3(64),    dim3(1024), 0, stream, out, (uint32_t*)ring);
  hipLaunchKernelGGL(k_fold,  dim3(41),    dim3(256), 0, stream, Wih, bih, Wk, bk, Wmu, bmu, Wlv, blv, Wne, bne,
                     Aih, cih, Ak, ck, Amu2, cmu2, Alv2, clv2);
  hipLaunchKernelGGL(k_h0,    dim3(32),    dim3(256), 0, stream, z, Wzh, bzh, ring);
  hipLaunchKernelGGL(k_wcvt,  dim3(128),   dim3(256), 0, stream, Wq, wqf, 32);
  hipLaunchKernelGGL(k_wcvt,  dim3(384),   dim3(256), 0, stream, Whh, whhf, 96);
  hipLaunchKernelGGL(k_kfrag, dim3(16384), dim3(256), 0, stream, tpos, Ak, ck, Kf);
  hipLaunchKernelGGL(k_gru,   dim3(64),    dim3(256), 0, stream, tpos, Aih, cih, bhh, whhf, ring, Hs);
  hipLaunchKernelGGL(k_qattn, dim3(4096),  dim3(256), 0, stream, Hs, wqf, bq, Kf, par, tpos,
                     Wmu, Wlv, Ws, bs, Amu2, cmu2, Alv2, clv2, out);
}